// Round 6
// baseline (243.754 us; speedup 1.0000x reference)
//
#include <hip/hip_runtime.h>
#include <hip/hip_bf16.h>

// StyleLoss — x (1,512,64,64) fp32, target (512,256,256) fp32 -> scalar loss.
// loss = mean_{i,a,b}( (g_full[(i+a)%512,(i+b)%512]/2^20 - target[i,a,b])^2 ) * 1e6
//
// R9: keep R8's validated algebra (absmax 0.0):
//   Sum(g~-t)^2 = Sum_rc n*g~^2 - 2*Sum_rc g~*S1 + Sum t^2,
//   S1[r,c] = sum_a t[(r-a)&511, a, (c-(r-a))&511] (valid b<256),
//   n(r,c) = 256 - min((r-c)&511,(c-r)&511).
// R8 failed perf because S1 used 8x ds_read_b32 per segment (DS-issue bound,
// ~50us/CU). R9 deletes LDS from the S1 inner loop: lane owns contiguous cols
// [4L,4L+4) u [4L+256,4L+260); source for its 4 cols is ONE unaligned 16B
// global load at seg[(4L-i)&255] (rotate the ADDRESS, not the data). Set
// select k0=bit8((4L-i)&511) via predicated FMA; <=1 wrap lane/wave takes a
// 4-scalar path (element wraps to seg head, set flips). Zero DS per segment.
//
// Roles: blocks [0,512) = S1 rows (4 waves x 64 segments, BW-bound stream);
//        blocks [512,768) = gemm C=F*F^T (R8-verbatim, hidden under S1).
//
// ws: [0,4MB) fp32 g_part[4][512*512]; [4,5MB) fp32 S1[512][512];
//     fp32 t2part[512]; fp32 partial2[256].

typedef __attribute__((ext_vector_type(8))) short bf16x8;   // 8 bf16 in 4 VGPRs
typedef __attribute__((ext_vector_type(4))) float f32x4;

#define CH 512
#define KDIM 4096
#define SPLITK 4

#define BM 64
#define BK 64
#define LDT 72   // padded LDS stride in bf16: 144 B (b128-aligned, 2-way alias = free)

static __device__ inline uint4 cvt8_bf16(float4 a, float4 b) {
    float f[8] = {a.x, a.y, a.z, a.w, b.x, b.y, b.z, b.w};
    union { ushort u[8]; uint4 v; } o;
#pragma unroll
    for (int i = 0; i < 8; ++i) {
        __hip_bfloat16 h = __float2bfloat16(f[i]);
        o.u[i] = *reinterpret_cast<ushort*>(&h);
    }
    return o.v;
}

// ---------------------------------------------------------------- fused ------
__global__ __launch_bounds__(256) void fused_main_kernel(const float* __restrict__ x,
                                                         const float* __restrict__ target,
                                                         float* __restrict__ g_part,
                                                         float* __restrict__ S1g,
                                                         float* __restrict__ t2part) {
    __shared__ __hip_bfloat16 a_tile[BM * LDT];
    __shared__ __hip_bfloat16 b_tile[BM * LDT];
    __shared__ float comb[4][512];         // cross-wave S1 combine (once per block)
    __shared__ float t2w[4];

    const int bid = blockIdx.x;
    const int tid = threadIdx.x;
    const int lane = tid & 63;
    const int w    = tid >> 6;

    if (bid >= 512) {
        // ======================== GEMM role (R8 verbatim) ========================
        const int gid = bid - 512;
        const int bm = gid & 7, bn = (gid >> 3) & 7, kz = gid >> 6;
        const int m    = lane & 15;
        const int q    = lane >> 4;       // quad: k offset q*8
        const int srow = tid >> 3;        // staging row 0..31 (+32 for p=1)
        const int scol = (tid & 7) * 8;   // 0..56 step 8

        f32x4 acc[4] = {};

        const int NT = (KDIM / SPLITK) / BK;            // 16 k-tiles per block
        const int k0base = kz * (KDIM / SPLITK);        // 1024 per split

        const float* arow0 = x + (size_t)(bm * 64 + srow) * KDIM + k0base + scol;
        const float* brow0 = x + (size_t)(bn * 64 + srow) * KDIM + k0base + scol;

        float4 pa[2][2], pb[2][2];
#pragma unroll
        for (int p = 0; p < 2; ++p) {
            const float* ap = arow0 + (size_t)p * 32 * KDIM;
            const float* bp = brow0 + (size_t)p * 32 * KDIM;
            pa[p][0] = *(const float4*)(ap);  pa[p][1] = *(const float4*)(ap + 4);
            pb[p][0] = *(const float4*)(bp);  pb[p][1] = *(const float4*)(bp + 4);
        }

        for (int kt = 0; kt < NT; ++kt) {
            if (kt > 0) __syncthreads();
#pragma unroll
            for (int p = 0; p < 2; ++p) {
                uint4 av = cvt8_bf16(pa[p][0], pa[p][1]);
                uint4 bv = cvt8_bf16(pb[p][0], pb[p][1]);
                uint* ap = (uint*)(a_tile + (srow + p * 32) * LDT + scol);
                ap[0] = av.x; ap[1] = av.y; ap[2] = av.z; ap[3] = av.w;
                uint* bp = (uint*)(b_tile + (srow + p * 32) * LDT + scol);
                bp[0] = bv.x; bp[1] = bv.y; bp[2] = bv.z; bp[3] = bv.w;
            }
            __syncthreads();
            if (kt + 1 < NT) {
                const int ko = (kt + 1) * BK;
#pragma unroll
                for (int p = 0; p < 2; ++p) {
                    const float* ap = arow0 + (size_t)p * 32 * KDIM + ko;
                    const float* bp = brow0 + (size_t)p * 32 * KDIM + ko;
                    pa[p][0] = *(const float4*)(ap);  pa[p][1] = *(const float4*)(ap + 4);
                    pb[p][0] = *(const float4*)(bp);  pb[p][1] = *(const float4*)(bp + 4);
                }
            }
#pragma unroll
            for (int ks = 0; ks < 2; ++ks) {
                const int kk = ks * 32 + q * 8;
                bf16x8 afrag = *(const bf16x8*)(a_tile + (w * 16 + m) * LDT + kk);
#pragma unroll
                for (int j = 0; j < 4; ++j) {
                    bf16x8 bfrag = *(const bf16x8*)(b_tile + (j * 16 + m) * LDT + kk);
                    acc[j] = __builtin_amdgcn_mfma_f32_16x16x32_bf16(afrag, bfrag, acc[j], 0, 0, 0);
                }
            }
        }

        // C/D layout: col = lane&15, row = (lane>>4)*4 + reg (verified m89/m91)
        float* gp = g_part + ((size_t)kz << 18);
        const int col = lane & 15;
        const int rq  = (lane >> 4) * 4;
#pragma unroll
        for (int j = 0; j < 4; ++j) {
#pragma unroll
            for (int reg = 0; reg < 4; ++reg) {
                const int rg = bm * 64 + w * 16 + rq + reg;
                const int cg = bn * 64 + j * 16 + col;
                gp[rg * CH + cg] = acc[j][reg];
            }
        }
        return;
    }

    // ======================== S1 role: one output row r per block ========================
    // Wave w handles segments a = 64w..64w+63 (i = (r-a)&511). Lane L owns cols
    // [4L,4L+4) (acc0) and [4L+256,4L+260) (acc1). Source for its 4 cols is
    // seg[(4L-i)&255 .. +3] (mod-256 wrap), one unaligned 16B load in the
    // common case; destination set = bit8((4L-i)&511), flipped for wrapped elems.
    const int r = bid;

    float4 acc0 = {0.f, 0.f, 0.f, 0.f};
    float4 acc1 = {0.f, 0.f, 0.f, 0.f};
    float t2 = 0.0f;

#pragma unroll 4
    for (int s = 0; s < 64; ++s) {
        const int a = w * 64 + s;
        const int i = (r - a) & 511;
        const int d = (4 * lane - i) & 511;
        const int b = d & 255;
        const int k0 = d >> 8;                         // 0 or 1
        const float* seg = target + ((size_t)i << 16) + (a << 8);

        if (b <= 252) {                                // common: all 4 elems same set
            float4 t;
            __builtin_memcpy(&t, seg + b, 16);         // unaligned 16B, in-bounds
            t2 += t.x * t.x + t.y * t.y + t.z * t.z + t.w * t.w;
            const float m0 = k0 ? 0.0f : 1.0f;
            const float m1 = 1.0f - m0;
            acc0.x = __builtin_fmaf(t.x, m0, acc0.x);
            acc0.y = __builtin_fmaf(t.y, m0, acc0.y);
            acc0.z = __builtin_fmaf(t.z, m0, acc0.z);
            acc0.w = __builtin_fmaf(t.w, m0, acc0.w);
            acc1.x = __builtin_fmaf(t.x, m1, acc1.x);
            acc1.y = __builtin_fmaf(t.y, m1, acc1.y);
            acc1.z = __builtin_fmaf(t.z, m1, acc1.z);
            acc1.w = __builtin_fmaf(t.w, m1, acc1.w);
        } else {                                       // <=1 lane/wave: window wraps
            const float mk0 = k0 ? 0.0f : 1.0f;        // acc0 weight, unwrapped elem
            const float mw0 = 1.0f - mk0;              // acc0 weight, wrapped elem
            float v[4];
            float m[4];
            v[0] = seg[b];                 m[0] = mk0;               // b <= 255: never wraps
            v[1] = seg[(b + 1) & 255];     m[1] = (b + 1 < 256) ? mk0 : mw0;
            v[2] = seg[(b + 2) & 255];     m[2] = (b + 2 < 256) ? mk0 : mw0;
            v[3] = seg[(b + 3) & 255];     m[3] = (b + 3 < 256) ? mk0 : mw0;
            t2 += v[0] * v[0] + v[1] * v[1] + v[2] * v[2] + v[3] * v[3];
            acc0.x = __builtin_fmaf(v[0], m[0], acc0.x);
            acc0.y = __builtin_fmaf(v[1], m[1], acc0.y);
            acc0.z = __builtin_fmaf(v[2], m[2], acc0.z);
            acc0.w = __builtin_fmaf(v[3], m[3], acc0.w);
            acc1.x = __builtin_fmaf(v[0], 1.0f - m[0], acc1.x);
            acc1.y = __builtin_fmaf(v[1], 1.0f - m[1], acc1.y);
            acc1.z = __builtin_fmaf(v[2], 1.0f - m[2], acc1.z);
            acc1.w = __builtin_fmaf(v[3], 1.0f - m[3], acc1.w);
        }
    }

    // cross-wave combine via LDS (once per block), then write S1 row + t2
    *(float4*)&comb[w][4 * lane]       = acc0;
    *(float4*)&comb[w][4 * lane + 256] = acc1;
#pragma unroll
    for (int off = 32; off > 0; off >>= 1) t2 += __shfl_xor(t2, off, 64);
    if (lane == 0) t2w[w] = t2;
    __syncthreads();
    const float s0 = comb[0][tid]       + comb[1][tid]       + comb[2][tid]       + comb[3][tid];
    const float s1 = comb[0][tid + 256] + comb[1][tid + 256] + comb[2][tid + 256] + comb[3][tid + 256];
    S1g[r * CH + tid]       = s0;
    S1g[r * CH + tid + 256] = s1;
    if (tid == 0) t2part[r] = t2w[0] + t2w[1] + t2w[2] + t2w[3];
}

// ---------------------------------------------------------------- final ------
// 256 blocks x 256 threads, 4 cells/thread: g~ = sum_k g_part / 2^20;
// acc += n(r,c)*g~^2 - 2*g~*S1.   n = 256 - min((r-c)&511,(c-r)&511).
__global__ __launch_bounds__(256) void final_partial_kernel(const float* __restrict__ g_part,
                                                            const float* __restrict__ S1g,
                                                            float* __restrict__ partial2) {
    const float gscale = 1.0f / 1048576.0f;
    const int tid = threadIdx.x, bid = blockIdx.x;
    const int lane = tid & 63, wv = tid >> 6;
    const int cell = (bid * 256 + tid) * 4;          // linear rc, row-aligned (512%4==0)
    const int r = cell >> 9, c0 = cell & 511;

    float4 g = *(const float4*)(g_part + cell);
#pragma unroll
    for (int sl = 1; sl < SPLITK; ++sl) {
        float4 v = *(const float4*)(g_part + sl * (CH * CH) + cell);
        g.x += v.x; g.y += v.y; g.z += v.z; g.w += v.w;
    }
    float4 s1 = *(const float4*)(S1g + cell);

    float gg[4] = {g.x, g.y, g.z, g.w};
    float ss[4] = {s1.x, s1.y, s1.z, s1.w};
    float acc = 0.0f;
#pragma unroll
    for (int j = 0; j < 4; ++j) {
        const int c  = c0 + j;
        const int d1 = (r - c) & 511;
        const int d2 = (c - r) & 511;
        const float n = (float)(256 - (d1 < d2 ? d1 : d2));
        const float gt = gg[j] * gscale;
        acc += n * gt * gt - 2.0f * gt * ss[j];
    }

#pragma unroll
    for (int off = 32; off > 0; off >>= 1) acc += __shfl_xor(acc, off, 64);
    __shared__ float wsum[4];
    if (lane == 0) wsum[wv] = acc;
    __syncthreads();
    if (tid == 0) partial2[bid] = wsum[0] + wsum[1] + wsum[2] + wsum[3];
}

// ---------------------------------------------------------------- finish -----
// out = (sum partial2[256] + sum t2part[512]) * WEIGHT/count
__global__ __launch_bounds__(256) void finish_kernel(const float* __restrict__ partial2,
                                                     const float* __restrict__ t2part,
                                                     float* __restrict__ out) {
    const float lscale = 1.0e6f / 33554432.0f;
    const int tid  = threadIdx.x;
    const int lane = tid & 63;
    const int wv   = tid >> 6;
    float s = partial2[tid] + t2part[tid] + t2part[tid + 256];
#pragma unroll
    for (int off = 32; off > 0; off >>= 1) s += __shfl_xor(s, off, 64);
    __shared__ float wsum[4];
    if (lane == 0) wsum[wv] = s;
    __syncthreads();
    if (tid == 0) out[0] = (wsum[0] + wsum[1] + wsum[2] + wsum[3]) * lscale;
}

// ---------------------------------------------------------------- launch -----
extern "C" void kernel_launch(void* const* d_in, const int* in_sizes, int n_in,
                              void* d_out, int out_size, void* d_ws, size_t ws_size,
                              hipStream_t stream) {
    const float* x      = (const float*)d_in[0];   // 2097152 fp32
    const float* target = (const float*)d_in[1];   // 33554432 fp32
    float* out = (float*)d_out;

    float* g_part   = (float*)d_ws;                     // 4 MB  [4][512*512]
    float* S1g      = g_part + SPLITK * CH * CH;        // 1 MB  [512][512]
    float* t2part   = S1g + CH * CH;                    // 2 KB
    float* partial2 = t2part + CH;                      // 1 KB

    fused_main_kernel<<<768, 256, 0, stream>>>(x, target, g_part, S1g, t2part);
    final_partial_kernel<<<256, 256, 0, stream>>>(g_part, S1g, partial2);
    finish_kernel<<<1, 256, 0, stream>>>(partial2, t2part, out);
}

// Round 7
// 207.314 us; speedup vs baseline: 1.1758x; 1.1758x over previous
//
#include <hip/hip_runtime.h>
#include <hip/hip_bf16.h>

// StyleLoss — x (1,512,64,64) fp32, target (512,256,256) fp32 -> scalar loss.
// loss = mean_{i,a,b}( (g_full[(i+a)%512,(i+b)%512]/2^20 - target[i,a,b])^2 ) * 1e6
//
// R10: algebra (validated absmax 0.0 in R8/R9):
//   Sum(g~-t)^2 = Sum_rc n*g~^2 - 2*Sum_rc g~*S1 + Sum t^2
//   S1[r,c] = sum_a t[(r-a)&511, a, (c-(r-a))&511 if <256], n=256-min(+-(r-c)&511).
// R8 S1 (branchy LDS gather) = 48us; R9 S1 (unaligned rotated global loads) =
// 100us, latency-bound even warm. R10 rebuilds the rotate:
//   - global: ALIGNED coalesced float4 per lane (R8's proven load side), 4-deep
//     prefetch ring.
//   - LDS strip layout: element p at lds[(p&3)*64 + (p>>2)]. Writes: 4x
//     ds_write_b32 at lane-CONSTANT addrs e*64+L (stride-1, conflict-free,
//     write2-mergeable). Reads: lane L col 4L+e <- addr ((e-i)&3)*64 +
//     ((b0+e)&255)>>2, stride-1 across lanes (2-way = free). 6 DS ops/segment.
//   - branch-free set select: k0 = bit8((4L-i)&511) ^ ((b0+e)>>8), cndmask.
// Roles: blocks [0,512) = S1 rows; [512,768) = gemm (R8 verbatim). All 768
// blocks co-resident (3/CU, 35KB LDS) -> target stream hidden under gemm.
//
// ws: [0,4MB) fp32 g_part[4][512*512]; [4,5MB) fp32 S1[512][512];
//     fp32 t2part[512]; fp32 partial2[256].

typedef __attribute__((ext_vector_type(8))) short bf16x8;   // 8 bf16 in 4 VGPRs
typedef __attribute__((ext_vector_type(4))) float f32x4;

#define CH 512
#define KDIM 4096
#define SPLITK 4

#define BM 64
#define BK 64
#define LDT 72   // padded LDS stride in bf16: 144 B (b128-aligned, 2-way alias = free)

static __device__ inline uint4 cvt8_bf16(float4 a, float4 b) {
    float f[8] = {a.x, a.y, a.z, a.w, b.x, b.y, b.z, b.w};
    union { ushort u[8]; uint4 v; } o;
#pragma unroll
    for (int i = 0; i < 8; ++i) {
        __hip_bfloat16 h = __float2bfloat16(f[i]);
        o.u[i] = *reinterpret_cast<ushort*>(&h);
    }
    return o.v;
}

// ---------------------------------------------------------------- fused ------
__global__ __launch_bounds__(256) void fused_main_kernel(const float* __restrict__ x,
                                                         const float* __restrict__ target,
                                                         float* __restrict__ g_part,
                                                         float* __restrict__ S1g,
                                                         float* __restrict__ t2part) {
    __shared__ __hip_bfloat16 a_tile[BM * LDT];
    __shared__ __hip_bfloat16 b_tile[BM * LDT];
    __shared__ float wavebuf[4][2][256];   // per-wave double-buffered strip store
    __shared__ float comb[4][512];         // cross-wave S1 combine
    __shared__ float t2w[4];

    const int bid = blockIdx.x;
    const int tid = threadIdx.x;
    const int lane = tid & 63;
    const int w    = tid >> 6;

    if (bid >= 512) {
        // ======================== GEMM role (R8 verbatim, proven) ========================
        const int gid = bid - 512;
        const int bm = gid & 7, bn = (gid >> 3) & 7, kz = gid >> 6;
        const int m    = lane & 15;
        const int q    = lane >> 4;       // quad: k offset q*8
        const int srow = tid >> 3;        // staging row 0..31 (+32 for p=1)
        const int scol = (tid & 7) * 8;   // 0..56 step 8

        f32x4 acc[4] = {};

        const int NT = (KDIM / SPLITK) / BK;            // 16 k-tiles per block
        const int k0base = kz * (KDIM / SPLITK);        // 1024 per split

        const float* arow0 = x + (size_t)(bm * 64 + srow) * KDIM + k0base + scol;
        const float* brow0 = x + (size_t)(bn * 64 + srow) * KDIM + k0base + scol;

        float4 pa[2][2], pb[2][2];
#pragma unroll
        for (int p = 0; p < 2; ++p) {
            const float* ap = arow0 + (size_t)p * 32 * KDIM;
            const float* bp = brow0 + (size_t)p * 32 * KDIM;
            pa[p][0] = *(const float4*)(ap);  pa[p][1] = *(const float4*)(ap + 4);
            pb[p][0] = *(const float4*)(bp);  pb[p][1] = *(const float4*)(bp + 4);
        }

        for (int kt = 0; kt < NT; ++kt) {
            if (kt > 0) __syncthreads();
#pragma unroll
            for (int p = 0; p < 2; ++p) {
                uint4 av = cvt8_bf16(pa[p][0], pa[p][1]);
                uint4 bv = cvt8_bf16(pb[p][0], pb[p][1]);
                uint* ap = (uint*)(a_tile + (srow + p * 32) * LDT + scol);
                ap[0] = av.x; ap[1] = av.y; ap[2] = av.z; ap[3] = av.w;
                uint* bp = (uint*)(b_tile + (srow + p * 32) * LDT + scol);
                bp[0] = bv.x; bp[1] = bv.y; bp[2] = bv.z; bp[3] = bv.w;
            }
            __syncthreads();
            if (kt + 1 < NT) {
                const int ko = (kt + 1) * BK;
#pragma unroll
                for (int p = 0; p < 2; ++p) {
                    const float* ap = arow0 + (size_t)p * 32 * KDIM + ko;
                    const float* bp = brow0 + (size_t)p * 32 * KDIM + ko;
                    pa[p][0] = *(const float4*)(ap);  pa[p][1] = *(const float4*)(ap + 4);
                    pb[p][0] = *(const float4*)(bp);  pb[p][1] = *(const float4*)(bp + 4);
                }
            }
#pragma unroll
            for (int ks = 0; ks < 2; ++ks) {
                const int kk = ks * 32 + q * 8;
                bf16x8 afrag = *(const bf16x8*)(a_tile + (w * 16 + m) * LDT + kk);
#pragma unroll
                for (int j = 0; j < 4; ++j) {
                    bf16x8 bfrag = *(const bf16x8*)(b_tile + (j * 16 + m) * LDT + kk);
                    acc[j] = __builtin_amdgcn_mfma_f32_16x16x32_bf16(afrag, bfrag, acc[j], 0, 0, 0);
                }
            }
        }

        // C/D layout: col = lane&15, row = (lane>>4)*4 + reg (verified m89/m91)
        float* gp = g_part + ((size_t)kz << 18);
        const int col = lane & 15;
        const int rq  = (lane >> 4) * 4;
#pragma unroll
        for (int j = 0; j < 4; ++j) {
#pragma unroll
            for (int reg = 0; reg < 4; ++reg) {
                const int rg = bm * 64 + w * 16 + rq + reg;
                const int cg = bn * 64 + j * 16 + col;
                gp[rg * CH + cg] = acc[j][reg];
            }
        }
        return;
    }

    // ======================== S1 role: one output row r per block ========================
    // Wave w: segments a = 64w+s, s=0..63; i = (r-a)&511; seg = t[i,a,0..255].
    // Lane L: loads seg[4L..4L+3] (aligned float4), strip-stores to LDS,
    // then gathers its own columns' sources and accumulates into
    // accA[e] (col 4L+e) / accB[e] (col 256+4L+e) selected by k0 (branch-free).
    const int r = bid;
    const float4* tgt4 = (const float4*)target;

    float accA[4] = {}, accB[4] = {};
    float t2 = 0.0f;
    float* bufw = &wavebuf[w][0][0];                 // [2][256]

    float4 pre[4];
#pragma unroll
    for (int e = 0; e < 4; ++e) {
        const int a = 64 * w + e;
        const int i = (r - a) & 511;
        pre[e] = tgt4[((size_t)i << 14) + (a << 6) + lane];
    }

    for (int s0 = 0; s0 < 64; s0 += 4) {
        float4 cur[4];
#pragma unroll
        for (int e = 0; e < 4; ++e) cur[e] = pre[e];
        if (s0 + 4 < 64) {
#pragma unroll
            for (int e = 0; e < 4; ++e) {
                const int a = 64 * w + s0 + 4 + e;
                const int i = (r - a) & 511;
                pre[e] = tgt4[((size_t)i << 14) + (a << 6) + lane];
            }
        }
#pragma unroll
        for (int u = 0; u < 4; ++u) {
            const int s = s0 + u;
            const int a = 64 * w + s;
            const int i = (r - a) & 511;
            const float4 v = cur[u];
            t2 += v.x * v.x + v.y * v.y + v.z * v.z + v.w * v.w;

            float* buf = bufw + ((s & 1) << 8);      // double buffer
            buf[lane]       = v.x;                   // strip e: addr e*64+L (const/lane)
            buf[64 + lane]  = v.y;
            buf[128 + lane] = v.z;
            buf[192 + lane] = v.w;

            const int b0  = (4 * lane - i) & 255;    // source pos for col 4L (mod 256)
            const int k00 = ((4 * lane - i) & 511) >> 8;
#pragma unroll
            for (int e = 0; e < 4; ++e) {
                const int pe   = b0 + e;             // <= 258
                const int pos  = pe & 255;
                const int k0   = k00 ^ (pe >> 8);    // set select, flips on wrap
                const float val = buf[(((e - i) & 3) << 6) | (pos >> 2)];
                accA[e] += k0 ? 0.0f : val;
                accB[e] += k0 ? val : 0.0f;
            }
        }
    }

    // cross-wave combine via LDS (once per block), then write S1 row + t2
    *(float4*)&comb[w][4 * lane]       = *(float4*)accA;
    *(float4*)&comb[w][4 * lane + 256] = *(float4*)accB;
#pragma unroll
    for (int off = 32; off > 0; off >>= 1) t2 += __shfl_xor(t2, off, 64);
    if (lane == 0) t2w[w] = t2;
    __syncthreads();
    const float s0c = comb[0][tid]       + comb[1][tid]       + comb[2][tid]       + comb[3][tid];
    const float s1c = comb[0][tid + 256] + comb[1][tid + 256] + comb[2][tid + 256] + comb[3][tid + 256];
    S1g[r * CH + tid]       = s0c;
    S1g[r * CH + tid + 256] = s1c;
    if (tid == 0) t2part[r] = t2w[0] + t2w[1] + t2w[2] + t2w[3];
}

// ---------------------------------------------------------------- final ------
// 256 blocks x 256 threads, 4 cells/thread: g~ = sum_k g_part / 2^20;
// acc += n(r,c)*g~^2 - 2*g~*S1.   n = 256 - min((r-c)&511,(c-r)&511).
__global__ __launch_bounds__(256) void final_partial_kernel(const float* __restrict__ g_part,
                                                            const float* __restrict__ S1g,
                                                            float* __restrict__ partial2) {
    const float gscale = 1.0f / 1048576.0f;
    const int tid = threadIdx.x, bid = blockIdx.x;
    const int lane = tid & 63, wv = tid >> 6;
    const int cell = (bid * 256 + tid) * 4;          // linear rc, row-aligned (512%4==0)
    const int r = cell >> 9, c0 = cell & 511;

    float4 g = *(const float4*)(g_part + cell);
#pragma unroll
    for (int sl = 1; sl < SPLITK; ++sl) {
        float4 v = *(const float4*)(g_part + sl * (CH * CH) + cell);
        g.x += v.x; g.y += v.y; g.z += v.z; g.w += v.w;
    }
    float4 s1 = *(const float4*)(S1g + cell);

    float gg[4] = {g.x, g.y, g.z, g.w};
    float ss[4] = {s1.x, s1.y, s1.z, s1.w};
    float acc = 0.0f;
#pragma unroll
    for (int j = 0; j < 4; ++j) {
        const int c  = c0 + j;
        const int d1 = (r - c) & 511;
        const int d2 = (c - r) & 511;
        const float n = (float)(256 - (d1 < d2 ? d1 : d2));
        const float gt = gg[j] * gscale;
        acc += n * gt * gt - 2.0f * gt * ss[j];
    }

#pragma unroll
    for (int off = 32; off > 0; off >>= 1) acc += __shfl_xor(acc, off, 64);
    __shared__ float wsum[4];
    if (lane == 0) wsum[wv] = acc;
    __syncthreads();
    if (tid == 0) partial2[bid] = wsum[0] + wsum[1] + wsum[2] + wsum[3];
}

// ---------------------------------------------------------------- finish -----
// out = (sum partial2[256] + sum t2part[512]) * WEIGHT/count
__global__ __launch_bounds__(256) void finish_kernel(const float* __restrict__ partial2,
                                                     const float* __restrict__ t2part,
                                                     float* __restrict__ out) {
    const float lscale = 1.0e6f / 33554432.0f;
    const int tid  = threadIdx.x;
    const int lane = tid & 63;
    const int wv   = tid >> 6;
    float s = partial2[tid] + t2part[tid] + t2part[tid + 256];
#pragma unroll
    for (int off = 32; off > 0; off >>= 1) s += __shfl_xor(s, off, 64);
    __shared__ float wsum[4];
    if (lane == 0) wsum[wv] = s;
    __syncthreads();
    if (tid == 0) out[0] = (wsum[0] + wsum[1] + wsum[2] + wsum[3]) * lscale;
}

// ---------------------------------------------------------------- launch -----
extern "C" void kernel_launch(void* const* d_in, const int* in_sizes, int n_in,
                              void* d_out, int out_size, void* d_ws, size_t ws_size,
                              hipStream_t stream) {
    const float* x      = (const float*)d_in[0];   // 2097152 fp32
    const float* target = (const float*)d_in[1];   // 33554432 fp32
    float* out = (float*)d_out;

    float* g_part   = (float*)d_ws;                     // 4 MB  [4][512*512]
    float* S1g      = g_part + SPLITK * CH * CH;        // 1 MB  [512][512]
    float* t2part   = S1g + CH * CH;                    // 2 KB
    float* partial2 = t2part + CH;                      // 1 KB

    fused_main_kernel<<<768, 256, 0, stream>>>(x, target, g_part, S1g, t2part);
    final_partial_kernel<<<256, 256, 0, stream>>>(g_part, S1g, partial2);
    finish_kernel<<<1, 256, 0, stream>>>(partial2, t2part, out);
}